// Round 1
// baseline (448.442 us; speedup 1.0000x reference)
//
#include <hip/hip_runtime.h>

// Problem constants (from reference): B=4096, K=128, D=512, V=128000, sparse=1 always.
// out[b,k] = dot(weight[indices[b,k]], inp[b]) + bias[indices[b,k]]
//
// Strategy: one block per sample b (256 threads = 4 waves). Each lane caches its
// 8 inp floats in registers (inp row reused K=128 times). One wave per output
// element: two contiguous dwordx4 loads of the gathered weight row (64 lanes x
// 16B = 1KiB per instruction), 8 FMAs, 6-step shfl_xor reduce, lane 0 stores.
// Memory-bound on the ~262MB weight gather (4x reuse served mostly by L3).

constexpr int Kc = 128;
constexpr int Dc = 512;

__global__ __launch_bounds__(256) void SparseProjection_kernel(
    const float* __restrict__ inp,      // [B, D]
    const int*   __restrict__ indices,  // [B, K]
    const float* __restrict__ weight,   // [V, D]
    const float* __restrict__ bias,     // [V]
    float*       __restrict__ out)      // [B, K]
{
    const int b    = blockIdx.x;
    const int tid  = threadIdx.x;
    const int lane = tid & 63;
    const int wave = tid >> 6;   // 0..3

    // inp row for this block, cached in registers per lane.
    // Lane covers floats [lane*4, lane*4+4) and [256 + lane*4, 256 + lane*4 + 4).
    const float4* inp_row = (const float4*)(inp + (size_t)b * Dc);
    const float4 a0 = inp_row[lane];
    const float4 a1 = inp_row[64 + lane];

    const int* idx_base  = indices + (size_t)b * Kc;
    float*     out_base  = out     + (size_t)b * Kc;

    // Each wave handles 32 consecutive k's.
    #pragma unroll 4
    for (int i = 0; i < 32; ++i) {
        const int k   = wave * 32 + i;        // wave-uniform
        const int idx = idx_base[k];          // wave-uniform -> scalar load
        const float4* wrow = (const float4*)(weight + (size_t)idx * Dc);

        const float4 w0 = wrow[lane];         // floats [0,256): contiguous across wave
        const float4 w1 = wrow[64 + lane];    // floats [256,512)

        float s = a0.x * w0.x + a0.y * w0.y + a0.z * w0.z + a0.w * w0.w
                + a1.x * w1.x + a1.y * w1.y + a1.z * w1.z + a1.w * w1.w;

        // Butterfly reduction across the 64-lane wave.
        #pragma unroll
        for (int off = 32; off > 0; off >>= 1)
            s += __shfl_xor(s, off, 64);

        if (lane == 0)
            out_base[k] = s + bias[idx];
    }
}

extern "C" void kernel_launch(void* const* d_in, const int* in_sizes, int n_in,
                              void* d_out, int out_size, void* d_ws, size_t ws_size,
                              hipStream_t stream) {
    const float* inp     = (const float*)d_in[0];   // [4096, 512] f32
    const int*   indices = (const int*)  d_in[1];   // [4096, 128] int
    // d_in[2] = sparse flag (always 1) -- dense branch is dead code.
    const float* weight  = (const float*)d_in[3];   // [128000, 512] f32
    const float* bias    = (const float*)d_in[4];   // [128000] f32
    float*       out     = (float*)d_out;           // [4096, 128] f32

    const int B = in_sizes[0] / Dc;                 // 4096
    SparseProjection_kernel<<<B, 256, 0, stream>>>(inp, indices, weight, bias, out);
}